// Round 8
// baseline (591.469 us; speedup 1.0000x reference)
//
#include <hip/hip_runtime.h>
#include <hip/hip_bf16.h>

// Problem constants
constexpr int Bb = 8, Ll = 2048, Ww = 1024;
constexpr int BL = Bb * Ll;              // 16384

typedef short bf16x8 __attribute__((ext_vector_type(8)));
typedef float f32x4  __attribute__((ext_vector_type(4)));

// ---------- bf16 helpers ----------
__device__ inline unsigned short f2bf(float f) {
    union { float f; unsigned u; } v; v.f = f;
    unsigned u = v.u;
    unsigned r = (u + 0x7fffu + ((u >> 16) & 1u)) >> 16;
    return (unsigned short)r;
}
__device__ inline float bf2f(unsigned short h) {
    union { unsigned u; float f; } v; v.u = ((unsigned)h) << 16;
    return v.f;
}
// lerp two packed bf16 pairs -> packed bf16 pair
__device__ inline unsigned lerp_pair(unsigned pa, unsigned pb, float w0, float w1) {
    union { unsigned u; float f; } alo, ahi, blo, bhi;
    alo.u = pa << 16;  ahi.u = pa & 0xffff0000u;
    blo.u = pb << 16;  bhi.u = pb & 0xffff0000u;
    float hlo = w0 * alo.f + w1 * blo.f;
    float hhi = w0 * ahi.f + w1 * bhi.f;
    union { __hip_bfloat162 h2; unsigned u; } r;
    r.h2 = __float22bfloat162_rn(float2{hlo, hhi});
    return r.u;
}

// ---------- kernel 1: fused prep = offsets (blocks 0..4095) + wconv (4096..4159)
//                      + mask dtype probe (4160..4175) ----------
__global__ __launch_bounds__(256) void prep_kernel(
    const float* __restrict__ x, const float* __restrict__ w_off, const float* __restrict__ b_off,
    const float* __restrict__ conv_w, const void* __restrict__ mraw,
    unsigned short* __restrict__ x_bf, float4* __restrict__ pk,
    unsigned short* __restrict__ w_bf, int* __restrict__ flags)
{
    const int blk = blockIdx.x;
    const int tid = threadIdx.x;
    if (blk < 4096) {
        // ---- offsets + x -> bf16 (one wave per row) ----
        const int wave = tid >> 6, lane = tid & 63;
        const int bl = blk * 4 + wave;
        const int l = bl & (Ll - 1);
        const int c0 = lane * 16;

        const float* xr = x + (size_t)bl * Ww + c0;
        float4 v0 = *(const float4*)(xr + 0);
        float4 v1 = *(const float4*)(xr + 4);
        float4 v2 = *(const float4*)(xr + 8);
        float4 v3 = *(const float4*)(xr + 12);
        float xv[16] = { v0.x,v0.y,v0.z,v0.w, v1.x,v1.y,v1.z,v1.w,
                         v2.x,v2.y,v2.z,v2.w, v3.x,v3.y,v3.z,v3.w };

        uint4 pa, pb;
        unsigned* pu = (unsigned*)&pa;
        #pragma unroll
        for (int j = 0; j < 4; j++) pu[j] = (unsigned)f2bf(xv[j*2]) | ((unsigned)f2bf(xv[j*2+1]) << 16);
        pu = (unsigned*)&pb;
        #pragma unroll
        for (int j = 0; j < 4; j++) pu[j] = (unsigned)f2bf(xv[8+j*2]) | ((unsigned)f2bf(xv[8+j*2+1]) << 16);
        *(uint4*)&x_bf[(size_t)bl * Ww + c0]     = pa;
        *(uint4*)&x_bf[(size_t)bl * Ww + c0 + 8] = pb;

        float acc[5] = {0.f, 0.f, 0.f, 0.f, 0.f};
        const float* wp = w_off + (size_t)c0 * 5;
        #pragma unroll
        for (int j = 0; j < 16; j++) {
            #pragma unroll
            for (int k = 0; k < 5; k++) acc[k] += xv[j] * wp[j * 5 + k];
        }
        #pragma unroll
        for (int k = 0; k < 5; k++)
            #pragma unroll
            for (int off = 32; off; off >>= 1) acc[k] += __shfl_xor(acc[k], off);

        if (lane < 5) {
            float s = (lane == 0) ? acc[0] : (lane == 1) ? acc[1] : (lane == 2) ? acc[2]
                    : (lane == 3) ? acc[3] : acc[4];
            s += b_off[lane];
            float offv = tanhf(s) * 2.0f;
            float pos = (float)l + (float)(lane - 2) + offv;
            float p0 = floorf(pos);
            float frac = pos - p0;
            int i0 = (int)p0;
            int i1 = i0 + 1;
            int ok0 = (i0 >= 0) && (i0 < Ll);
            int ok1 = (i1 >= 0) && (i1 < Ll);
            float4 pkv;
            pkv.x = __int_as_float(min(max(i0, 0), Ll - 1));
            pkv.y = __int_as_float(min(max(i1, 0), Ll - 1));
            pkv.z = ok0 ? (1.0f - frac) : 0.0f;
            pkv.w = ok1 ? frac : 0.0f;
            pk[bl * 5 + lane] = pkv;
        }
    } else if (blk < 4160) {
        // ---- conv_w fp32 [g][o][c][k] -> plain bf16 W'[go][k*512+c] ----
        const int bb = blk - 4096;               // 0..63
        for (int i = bb * 256 + tid; i < 1024 * 320; i += 64 * 256) {
            const int go = i / 320;
            const int idx = i - go * 320;
            const int kk8 = idx * 8;             // 8-channel chunk start within row
            const int ktap = kk8 >> 9;
            const int c0 = kk8 & 511;
            const float* src = conv_w + ((size_t)go * 512 + c0) * 5 + ktap;
            ushort4 lo, hi;
            lo.x = f2bf(src[0]);  lo.y = f2bf(src[5]);  lo.z = f2bf(src[10]); lo.w = f2bf(src[15]);
            hi.x = f2bf(src[20]); hi.y = f2bf(src[25]); hi.z = f2bf(src[30]); hi.w = f2bf(src[35]);
            *(ushort4*)&w_bf[(size_t)go * 2560 + kk8]     = lo;
            *(ushort4*)&w_bf[(size_t)go * 2560 + kk8 + 4] = hi;
        }
    } else {
        // ---- mask dtype probe ----
        const unsigned char* mb = (const unsigned char*)mraw;
        const unsigned* mw = (const unsigned*)mraw;
        int gid = (blk - 4160) * 256 + tid;      // 4096 threads
        int nonint = 0, notf = 0, hasf = 0;
        for (int i = gid; i < BL; i += 4096) { if ((i & 3) && mb[i]) nonint = 1; }
        for (int i = gid; i < BL / 4; i += 4096) {
            unsigned w = mw[i];
            if (w == 0x3f800000u) hasf = 1; else if (w) notf = 1;
        }
        if (nonint) atomicOr(&flags[0], 1);
        if (notf)   atomicOr(&flags[1], 1);
        if (hasf)   atomicOr(&flags[2], 1);
    }
}

// ---------- kernel 2: barrier-free fused deform GEMM -> h ----------
// No LDS, no __syncthreads. Wave = 32 rows x 128 cols; block = 4 waves = 128 rows.
// A fragments lerped in registers from x_bf; B fragments loaded to registers from
// plain W'[col][kk] (4 waves/block share the same frags via L1). Compiler is free
// to run loads ahead under vmcnt — the AITER-style pipeline the barrier forbade.
__global__ __launch_bounds__(256, 2) void gemm_kernel(
    const unsigned short* __restrict__ x_bf, const unsigned short* __restrict__ w_bf,
    const float4* __restrict__ pk, const float* __restrict__ conv_b,
    unsigned short* __restrict__ h)
{
    const int tid = threadIdx.x;
    const int mt = blockIdx.x;            // 0..127 (128-row block)
    const int nc = blockIdx.y;            // 0..7  (128-col tile; g = nc>>2)
    const int b = mt >> 4;
    const int lane = tid & 63, wave = tid >> 6;
    const int l15 = lane & 15, l4 = lane >> 4;
    const int row0 = mt * 128 + wave * 32;
    const int g = nc >> 2;
    const int colbase = nc * 128;

    f32x4 acc[2][8];
    #pragma unroll
    for (int i = 0; i < 2; i++)
        #pragma unroll
        for (int j = 0; j < 8; j++) acc[i][j] = (f32x4){0.f, 0.f, 0.f, 0.f};

    // B row base pointers (8 j-frags), invariant over k/cs
    const unsigned short* wrow[8];
    #pragma unroll
    for (int j = 0; j < 8; j++)
        wrow[j] = w_bf + (size_t)(colbase + j * 16 + l15) * 2560 + l4 * 8;

    for (int k = 0; k < 5; ++k) {
        // per-k row metadata (2 row-frags of 16)
        unsigned off0[2], off1[2];
        float w0r[2], w1r[2];
        #pragma unroll
        for (int i = 0; i < 2; i++) {
            const int bl = row0 + i * 16 + l15;
            float4 pkv = pk[bl * 5 + k];
            const int i0 = __float_as_int(pkv.x), i1 = __float_as_int(pkv.y);
            off0[i] = (unsigned)(((b << 11) + i0) * Ww + g * 512 + l4 * 8);
            off1[i] = (unsigned)(((b << 11) + i1) * Ww + g * 512 + l4 * 8);
            w0r[i] = pkv.z; w1r[i] = pkv.w;
        }
        const int kb = k * 512;
        for (int cs = 0; cs < 16; ++cs) {
            const int ch = cs * 32;
            // A fragments (register lerp)
            bf16x8 af[2];
            #pragma unroll
            for (int i = 0; i < 2; i++) {
                const uint4 ua = *(const uint4*)(x_bf + off0[i] + ch);
                const uint4 ub = *(const uint4*)(x_bf + off1[i] + ch);
                union { unsigned u[4]; bf16x8 v; } fa;
                fa.u[0] = lerp_pair(ua.x, ub.x, w0r[i], w1r[i]);
                fa.u[1] = lerp_pair(ua.y, ub.y, w0r[i], w1r[i]);
                fa.u[2] = lerp_pair(ua.z, ub.z, w0r[i], w1r[i]);
                fa.u[3] = lerp_pair(ua.w, ub.w, w0r[i], w1r[i]);
                af[i] = fa.v;
            }
            // B fragments direct from global (L1-shared across waves)
            bf16x8 bfr[8];
            #pragma unroll
            for (int j = 0; j < 8; j++)
                bfr[j] = *(const bf16x8*)(wrow[j] + kb + ch);
            #pragma unroll
            for (int i = 0; i < 2; i++)
                #pragma unroll
                for (int j = 0; j < 8; j++)
                    acc[i][j] = __builtin_amdgcn_mfma_f32_16x16x32_bf16(af[i], bfr[j], acc[i][j], 0, 0, 0);
        }
    }
    // epilogue: + conv_b, store h bf16
    #pragma unroll
    for (int j = 0; j < 8; j++) {
        const int col = colbase + j * 16 + l15;
        const float bias = conv_b[col];
        #pragma unroll
        for (int i = 0; i < 2; i++) {
            const int r0 = row0 + i * 16 + l4 * 4;
            #pragma unroll
            for (int rr = 0; rr < 4; rr++)
                h[(size_t)(r0 + rr) * Ww + col] = f2bf(acc[i][j][rr] + bias);
        }
    }
}

// ---------- kernel 3: LayerNorm + inline mask + pooled partials + lengths ----------
// 64 rows per block (16 per wave) -> 4x fewer pooled atomics than R7.
__global__ __launch_bounds__(256) void lnpool_kernel(
    const unsigned short* __restrict__ h, const float* __restrict__ gamma,
    const void* __restrict__ mraw, const int* __restrict__ flags,
    float* __restrict__ pooled, float* __restrict__ lengths)
{
    const int tid = threadIdx.x;
    const int wave = tid >> 6, lane = tid & 63;
    const int c0 = lane * 16;
    const int bl0 = blockIdx.x * 64 + wave * 16;
    const int b = bl0 >> 11;

    const unsigned char* mb = (const unsigned char*)mraw;
    const unsigned* mw = (const unsigned*)mraw;
    const int is_f32  = (!flags[1]) && flags[2];
    const int is_bool = (!is_f32) && flags[0];

    float g16[16];
    #pragma unroll
    for (int j = 0; j < 4; j++) {
        float4 gv = *(const float4*)(gamma + c0 + j * 4);
        g16[j*4+0] = gv.x; g16[j*4+1] = gv.y; g16[j*4+2] = gv.z; g16[j*4+3] = gv.w;
    }
    float pacc[16];
    #pragma unroll
    for (int j = 0; j < 16; j++) pacc[j] = 0.f;
    float cnt = 0.f;

    for (int r = 0; r < 16; r++) {
        const int bl = bl0 + r;
        const int masked = is_bool ? (mb[bl] != 0) : (mw[bl] != 0u);
        const float m = masked ? 0.0f : 1.0f;
        cnt += m;
        const uint4 ha = *(const uint4*)(h + (size_t)bl * Ww + c0);
        const uint4 hb = *(const uint4*)(h + (size_t)bl * Ww + c0 + 8);
        float hf[16];
        const unsigned* pw = (const unsigned*)&ha;
        #pragma unroll
        for (int j = 0; j < 4; j++) {
            union { unsigned u; float f; } lo, hi;
            lo.u = pw[j] << 16; hi.u = pw[j] & 0xffff0000u;
            hf[j*2] = lo.f; hf[j*2+1] = hi.f;
        }
        pw = (const unsigned*)&hb;
        #pragma unroll
        for (int j = 0; j < 4; j++) {
            union { unsigned u; float f; } lo, hi;
            lo.u = pw[j] << 16; hi.u = pw[j] & 0xffff0000u;
            hf[8+j*2] = lo.f; hf[8+j*2+1] = hi.f;
        }
        float s1 = 0.f, s2 = 0.f;
        #pragma unroll
        for (int j = 0; j < 16; j++) { s1 += hf[j]; s2 += hf[j] * hf[j]; }
        #pragma unroll
        for (int off = 32; off; off >>= 1) {
            s1 += __shfl_xor(s1, off);
            s2 += __shfl_xor(s2, off);
        }
        const float mu = s1 * (1.0f / 1024.0f);
        const float var = s2 * (1.0f / 1024.0f) - mu * mu;
        const float rstd = rsqrtf(var + 1e-5f) * m;       // mask by multiply
        #pragma unroll
        for (int j = 0; j < 16; j++) pacc[j] += (hf[j] - mu) * rstd * g16[j];
    }
    if (lane == 0) atomicAdd(&lengths[b], cnt);
    __shared__ float spool[4][1024];
    #pragma unroll
    for (int j = 0; j < 4; j++)
        *(float4*)&spool[wave][c0 + j * 4] = *(float4*)&pacc[j * 4];
    __syncthreads();
    const int ch = tid * 4;
    float4 a = *(float4*)&spool[0][ch];
    float4 bq = *(float4*)&spool[1][ch];
    float4 cq = *(float4*)&spool[2][ch];
    float4 dq = *(float4*)&spool[3][ch];
    atomicAdd(&pooled[b * Ww + ch + 0], a.x + bq.x + cq.x + dq.x);
    atomicAdd(&pooled[b * Ww + ch + 1], a.y + bq.y + cq.y + dq.y);
    atomicAdd(&pooled[b * Ww + ch + 2], a.z + bq.z + cq.z + dq.z);
    atomicAdd(&pooled[b * Ww + ch + 3], a.w + bq.w + cq.w + dq.w);
}

// ---------- kernel 4: projection (beta folded: + sum(beta*proj)) ----------
__global__ void final_kernel(const float* __restrict__ pooled, const float* __restrict__ lengths,
                             const float* __restrict__ beta, const float* __restrict__ proj_w,
                             const float* __restrict__ proj_b, float* __restrict__ out)
{
    int b = blockIdx.x;
    int tid = threadIdx.x;
    float dotP = 0.f, dotB = 0.f;
    for (int c = tid; c < Ww; c += 256) {
        dotP += pooled[b * Ww + c] * proj_w[c];
        dotB += beta[c] * proj_w[c];
    }
    for (int off = 32; off; off >>= 1) {
        dotP += __shfl_down(dotP, off);
        dotB += __shfl_down(dotB, off);
    }
    __shared__ float rp[4], rb[4];
    int wave = tid >> 6, lane = tid & 63;
    if (lane == 0) { rp[wave] = dotP; rb[wave] = dotB; }
    __syncthreads();
    if (tid == 0) {
        float Pt = rp[0] + rp[1] + rp[2] + rp[3];
        float Bt = rb[0] + rb[1] + rb[2] + rb[3];
        out[b] = Pt / fmaxf(lengths[b], 1.0f) + Bt + proj_b[0];
    }
}

// ---------- workspace layout (bytes, 16B-aligned) ----------
// pooled  @        0  (32768)   \
// flags   @    32768  (16)       } one memset (32832 B)
// lengths @    32784  (48)      /
// pk      @    32832  (1310720)
// w_bf    @  1343552  (5242880)   plain W'[1024][2560] bf16
// x_bf    @  6586432  (33554432)
// h       @ 40140864  (33554432)  -> total 73,695,296 B

extern "C" void kernel_launch(void* const* d_in, const int* in_sizes, int n_in,
                              void* d_out, int out_size, void* d_ws, size_t ws_size,
                              hipStream_t stream)
{
    const float* x      = (const float*)d_in[0];
    const void*  mask   = d_in[1];
    const float* w_off  = (const float*)d_in[2];
    const float* b_off  = (const float*)d_in[3];
    const float* conv_w = (const float*)d_in[4];
    const float* conv_b = (const float*)d_in[5];
    const float* gamma  = (const float*)d_in[6];
    const float* beta   = (const float*)d_in[7];
    const float* proj_w = (const float*)d_in[8];
    const float* proj_b = (const float*)d_in[9];
    float* out = (float*)d_out;

    char* ws = (char*)d_ws;
    float* pooled        = (float*)(ws + 0);
    int*   flags         = (int*)(ws + 32768);
    float* lengths       = (float*)(ws + 32784);
    float4* pk           = (float4*)(ws + 32832);
    unsigned short* w_bf = (unsigned short*)(ws + 1343552);
    unsigned short* x_bf = (unsigned short*)(ws + 6586432);
    unsigned short* h    = (unsigned short*)(ws + 40140864);

    hipMemsetAsync(pooled, 0, 32832, stream);
    prep_kernel<<<4176, 256, 0, stream>>>(x, w_off, b_off, conv_w, mask, x_bf, pk, w_bf, flags);
    gemm_kernel<<<dim3(128, 8), 256, 0, stream>>>(x_bf, w_bf, pk, conv_b, h);
    lnpool_kernel<<<256, 256, 0, stream>>>(h, gamma, mask, flags, pooled, lengths);
    final_kernel<<<8, 256, 0, stream>>>(pooled, lengths, beta, proj_w, proj_b, out);
}